// Round 2
// baseline (200.601 us; speedup 1.0000x reference)
//
#include <hip/hip_runtime.h>

// SelfAttention (SAGAN-style) on MI355X.
// B=2, C=64, C8=8, H=W=96, N=9216.  out = gamma * Attn(g,f,h) + x
//   K = f = (Wq/sq) x + bq   (pre-scaled by log2e; softmax in exp2 domain)
//   Q = g = (Wk/sk) x + bk
//   V = h = (Wv/sv) x + bv
// softmax over keys i; head_dim 8 (zero-padded), dv=64.
//
// R14: LDS-free main loop. R13 evidence: LDS=32KB did NOT yield 5 blocks/CU
// (occupancy stuck at 28%, dur only -8.6% = chain trim alone) -> the 5th
// 32KB block never co-schedules; tail of 128 blocks at 1/CU remains.
// Fix: per-lane V fragments are CONTIGUOUS 16B in VT16 (channel q31 /
// 32+q31, keys i+8hi..+8), so V goes global->reg directly (4x
// global_load_dwordx4 per round), replacing 4 gload_lds + 4 ds_read_b128.
// Main loop now has ZERO LDS ops / barriers; LDS = epilogue merge only
// (float SM[4][1152] = 18432B). __launch_bounds__(256,5) caps VGPR at 102
// -> 5 waves/SIMD -> 5 blocks/CU -> all 1152 blocks resident, no tail.
// V issued at round top, consumed after softmax (~250cy) -> L2 latency
// hidden; K double-buffered in regs so S-MFMA never waits.
// Numerics unchanged (M = |Q|*max|K'| - 12, f16 P, f32 lsum).

#define N_PIX 9216
#define N_B   2
#define N_C   64

typedef _Float16 half8  __attribute__((ext_vector_type(8)));
typedef float    float4v __attribute__((ext_vector_type(4)));
typedef float    float16v __attribute__((ext_vector_type(16)));
typedef int      int4v  __attribute__((ext_vector_type(4)));

#define LOG2E 1.44269504088896340736f
#define EXP_SHIFT 12.0f

// ---------------------------------------------------------------- k_sigma
__global__ __launch_bounds__(64) void k_sigma(const float* __restrict__ Wq,
                                              const float* __restrict__ Wk,
                                              const float* __restrict__ Wv,
                                              float* __restrict__ sig,
                                              unsigned* __restrict__ maxKu) {
  __shared__ float G8[8][8];
  __shared__ float Wl[64 * 64];
  __shared__ _Float16 Wh[64 * 80];
  __shared__ _Float16 Gh[64 * 80];
  const int t = threadIdx.x;
  const int mat = blockIdx.x;
  if (mat == 0 && t < 2) maxKu[t] = 0u;
  if (mat < 2) {
    const float* W = (mat == 0) ? Wq : Wk;
    const int i = t >> 3, j = t & 7;
    float g = 0.f;
    for (int c = 0; c < 64; ++c) g += W[i * 64 + c] * W[j * 64 + c];
    G8[i][j] = g;
    __syncthreads();
    const int L = t & 7;
    float G0[8], Gr[8];
    for (int k = 0; k < 8; ++k) { G0[k] = G8[L][k]; Gr[k] = G0[k]; }
    for (int it = 0; it < 8; ++it) {
      float g2[8] = {0, 0, 0, 0, 0, 0, 0, 0};
      for (int k = 0; k < 8; ++k) {
        float gik = Gr[k];
        for (int jj = 0; jj < 8; ++jj) g2[jj] += gik * __shfl(Gr[jj], k, 64);
      }
      float mx = 0.f;
      for (int jj = 0; jj < 8; ++jj) mx = fmaxf(mx, fabsf(g2[jj]));
      for (int d = 1; d < 8; d <<= 1) mx = fmaxf(mx, __shfl_xor(mx, d, 64));
      float r = 1.f / mx;
      for (int jj = 0; jj < 8; ++jj) Gr[jj] = g2[jj] * r;
    }
    float u = 0.f;
    for (int jj = 0; jj < 8; ++jj) u += Gr[jj];
    float y = 0.f;
    for (int k = 0; k < 8; ++k) y += G0[k] * __shfl(u, k, 64);
    float nu = u * y, de = u * u;
    for (int d = 1; d < 8; d <<= 1) { nu += __shfl_xor(nu, d, 64); de += __shfl_xor(de, d, 64); }
    if (t == 0) sig[mat] = sqrtf(nu / de);
  } else {
    for (int idx = t; idx < 4096; idx += 64) Wl[idx] = Wv[idx];
    __syncthreads();
    for (int idx = t; idx < 4096; idx += 64) Wh[(idx >> 6) * 80 + (idx & 63)] = (_Float16)Wl[idx];
    __syncthreads();
    const int lane15 = t & 15, quad = t >> 4;
    half8 fr[4][2];
    for (int rb = 0; rb < 4; ++rb)
      for (int kc = 0; kc < 2; ++kc)
        fr[rb][kc] = *(const half8*)&Wh[(lane15 + 16 * rb) * 80 + 32 * kc + 8 * quad];
    float4v D[4][4];
    for (int mb = 0; mb < 4; ++mb) for (int nb = 0; nb < 4; ++nb) D[mb][nb] = (float4v){0.f, 0.f, 0.f, 0.f};
    for (int kc = 0; kc < 2; ++kc)
      for (int mb = 0; mb < 4; ++mb)
        for (int nb = 0; nb < 4; ++nb)
          D[mb][nb] = __builtin_amdgcn_mfma_f32_16x16x32_f16(fr[mb][kc], fr[nb][kc], D[mb][nb], 0, 0, 0);
    for (int it = 0; it < 8; ++it) {
      float mx = 0.f;
      for (int mb = 0; mb < 4; ++mb) for (int nb = 0; nb < 4; ++nb) for (int r = 0; r < 4; ++r)
        mx = fmaxf(mx, fabsf(D[mb][nb][r]));
      for (int d = 1; d < 64; d <<= 1) mx = fmaxf(mx, __shfl_xor(mx, d, 64));
      float rs = 1.f / mx;
      for (int mb = 0; mb < 4; ++mb) for (int nb = 0; nb < 4; ++nb) for (int r = 0; r < 4; ++r)
        Gh[(4 * quad + r + 16 * mb) * 80 + lane15 + 16 * nb] = (_Float16)(D[mb][nb][r] * rs);
      __syncthreads();
      if (it == 7) break;
      for (int rb = 0; rb < 4; ++rb)
        for (int kc = 0; kc < 2; ++kc)
          fr[rb][kc] = *(const half8*)&Gh[(lane15 + 16 * rb) * 80 + 32 * kc + 8 * quad];
      for (int mb = 0; mb < 4; ++mb) for (int nb = 0; nb < 4; ++nb) D[mb][nb] = (float4v){0.f, 0.f, 0.f, 0.f};
      for (int kc = 0; kc < 2; ++kc)
        for (int mb = 0; mb < 4; ++mb)
          for (int nb = 0; nb < 4; ++nb)
            D[mb][nb] = __builtin_amdgcn_mfma_f32_16x16x32_f16(fr[mb][kc], fr[nb][kc], D[mb][nb], 0, 0, 0);
      __syncthreads();
    }
    float u = 0.f;
    for (int c = 0; c < 64; ++c) u += (float)Gh[t * 80 + c];
    float z = 0.f;
    for (int i2 = 0; i2 < 64; ++i2) z += Wl[i2 * 64 + t] * __shfl(u, i2, 64);
    float nu = z * z, de = u * u;
    for (int d = 1; d < 64; d <<= 1) { nu += __shfl_xor(nu, d, 64); de += __shfl_xor(de, d, 64); }
    if (t == 0) sig[2] = sqrtf(nu / de);
  }
}

// ---------------------------------------------------------------- k_fgh
__global__ __launch_bounds__(256) void k_fgh(const float* __restrict__ x,
                                             const float* __restrict__ Wq, const float* __restrict__ bq,
                                             const float* __restrict__ Wk, const float* __restrict__ bk,
                                             const float* __restrict__ Wv, const float* __restrict__ bv,
                                             const float* __restrict__ sig,
                                             _Float16* __restrict__ K16,
                                             _Float16* __restrict__ Q16,
                                             _Float16* __restrict__ VT16,
                                             unsigned* __restrict__ maxKu) {
  __shared__ _Float16 Wsh[80 * 64];
  __shared__ float bsh[80];
  const int t = threadIdx.x;
  const float iq = LOG2E / sig[0], ik = 1.0f / sig[1], iv = 1.0f / sig[2];
  for (int idx = t; idx < 80 * 64; idx += 256) {
    const int m = idx >> 6, c = idx & 63;
    float v;
    if (m < 8)       v = Wq[m * 64 + c] * iq;
    else if (m < 16) v = Wk[(m - 8) * 64 + c] * ik;
    else             v = Wv[(m - 16) * 64 + c] * iv;
    Wsh[idx] = (_Float16)v;
  }
  if (t < 80) {
    float v;
    if (t < 8)       v = bq[t] * LOG2E;
    else if (t < 16) v = bk[t - 8];
    else             v = bv[t - 16];
    bsh[t] = v;
  }
  __syncthreads();
  const int wave = t >> 6;
  const int lane = t & 63;
  const int lane15 = lane & 15, quad = lane >> 4;
  const int tile = blockIdx.x * 4 + wave;
  const int b = tile / 576;
  const int n = (tile % 576) * 16 + lane15;
  half8 wf[5][2];
  for (int mb = 0; mb < 5; ++mb)
    for (int kc = 0; kc < 2; ++kc)
      wf[mb][kc] = *(const half8*)&Wsh[(lane15 + 16 * mb) * 64 + 32 * kc + 8 * quad];
  float4v acc[5];
  for (int mb = 0; mb < 5; ++mb) acc[mb] = *(const float4v*)&bsh[16 * mb + 4 * quad];
  const float* xb = x + (size_t)b * N_C * N_PIX;
  for (int kc = 0; kc < 2; ++kc) {
    half8 bf;
    for (int j = 0; j < 8; ++j)
      bf[j] = (_Float16)xb[(size_t)(32 * kc + 8 * quad + j) * N_PIX + n];
    for (int mb = 0; mb < 5; ++mb)
      acc[mb] = __builtin_amdgcn_mfma_f32_16x16x32_f16(wf[mb][kc], bf, acc[mb], 0, 0, 0);
  }
  {
    _Float16* dstK = K16 + ((size_t)b * N_PIX + n) * 8;
    _Float16* dstQ = Q16 + ((size_t)b * N_PIX + n) * 8;
    for (int r = 0; r < 4; ++r) {
      const int m = 4 * quad + r;
      const _Float16 v = (_Float16)acc[0][r];
      if (m < 8) dstK[m] = v; else dstQ[m - 8] = v;
    }
  }
  for (int mb = 1; mb < 5; ++mb)
    for (int r = 0; r < 4; ++r) {
      const int c = 4 * quad + r + 16 * (mb - 1);
      VT16[((size_t)b * N_C + c) * N_PIX + n] = (_Float16)acc[mb][r];
    }
  float sq = 0.f;
  if (quad < 2)
    for (int r = 0; r < 4; ++r) sq += acc[0][r] * acc[0][r];
  sq += __shfl_xor(sq, 16, 64);
  for (int d = 1; d < 64; d <<= 1) sq = fmaxf(sq, __shfl_xor(sq, d, 64));
  if (lane == 0) atomicMax(&maxKu[b], __float_as_uint(sq));
}

// ---------------------------------------------------------------- k_attn
// 1152 blocks: tile = b*576 + jt*2 + h; block covers keys [4608h, +4608),
// 36 rounds of 128 keys (wave w owns 32). Everything in registers:
//   K: per-lane dwordx4, double-buffered (issued 1 round ahead).
//   V: 4x per-lane dwordx4 per round, issued at round top, consumed after
//      softmax (~250cy) -> L2 latency hidden in-wave.
// LDS only for the epilogue cross-wave merge: float SM[4][1152] = 18432 B.

// v_permlane32_swap_b32: a' = [a.lo, b.lo], b' = [a.hi, b.hi]
__device__ __forceinline__ void plswap(int& a, int& b) {
  asm("v_permlane32_swap_b32 %0, %1" : "+v"(a), "+v"(b));
}

__global__ __launch_bounds__(256, 5) void k_attn(const _Float16* __restrict__ K16,
                                                 const _Float16* __restrict__ Q16,
                                                 const _Float16* __restrict__ VT16,
                                                 const unsigned* __restrict__ maxKu,
                                                 float* __restrict__ Opart,
                                                 float* __restrict__ Lpart) {
  __shared__ float SMf[4][1152];          // 18432 B, epilogue only
  const int wave = threadIdx.x >> 6;
  const int lane = threadIdx.x & 63;
  const int q31 = lane & 31, hi = lane >> 5;
  const int tile = blockIdx.x;            // 0..1151
  const int b = tile / 576;
  const int rm = tile % 576;
  const int jb = (rm >> 1) * 32;
  const int h = rm & 1;
  const int kh = h * (N_PIX / 2);         // this block's key range base
  const _Float16* Kb = K16 + (size_t)b * N_PIX * 8;
  const _Float16* Vb = VT16 + (size_t)b * N_C * N_PIX;

  // Q B-frag: n=q31, k=8*hi+j; hi=0 lanes real (dims 0-7), hi=1 zero.
  half8 qf = {};
  if (hi == 0) qf = *(const half8*)(Q16 + ((size_t)b * N_PIX + jb + q31) * 8);
  const float maxK = sqrtf(__uint_as_float(maxKu[b]));
  float nq = 0.f;
#pragma unroll
  for (int j = 0; j < 8; ++j) nq += (float)qf[j] * (float)qf[j];
  nq += __shfl_xor(nq, 32, 64);
  const float M = sqrtf(nq) * maxK - EXP_SHIFT;
  float16v sinit;
#pragma unroll
  for (int r2 = 0; r2 < 16; ++r2) sinit[r2] = -M;

  float16v acc0 = {}, acc1 = {};
  float ls = 0.f;

  const int i0 = kh + 32 * wave;          // first key of this wave's stream
  // 32-bit element offsets against uniform bases (saddr + voffset form).
  const int okf = (i0 + q31) * 8;         // K: += 1024/round
  const int ov0 = q31 * N_PIX + i0 + 8 * hi;        // V ch q31:   += 128/round
  const int ov1 = ov0 + 32 * N_PIX;                 // V ch 32+q31

  int4v kcur = *(const int4v*)(Kb + okf); // round 0 K (hi lanes: dup, zeroed at use)

#pragma unroll 1
  for (int r = 0; r < 36; ++r) {
    const int ko = 128 * r;
    // V for THIS round (consumed after softmax), then K for NEXT round.
    const half8 v00 = *(const half8*)(Vb + ov0 + ko);
    const half8 v01 = *(const half8*)(Vb + ov0 + ko + 16);
    const half8 v10 = *(const half8*)(Vb + ov1 + ko);
    const half8 v11 = *(const half8*)(Vb + ov1 + ko + 16);
    // r=35: reads 2KB past K16[b=1] into Q16 region (allocated, unused).
    int4v knext = *(const int4v*)(Kb + okf + (r + 1) * 1024);
    // K A-frag: m=key=q31, k=8*hi+j; hi=1 lanes must be ZERO (dims 8-15).
    int4v kcz;
    kcz[0] = hi ? 0 : kcur[0];
    kcz[1] = hi ? 0 : kcur[1];
    kcz[2] = hi ? 0 : kcur[2];
    kcz[3] = hi ? 0 : kcur[3];
    const half8 kf = __builtin_bit_cast(half8, kcz);
    float16v s = __builtin_amdgcn_mfma_f32_32x32x16_f16(kf, qf, sinit, 0, 0, 0);
    int pk[8];
#pragma unroll
    for (int u = 0; u < 8; ++u) {
      const float p0 = __builtin_amdgcn_exp2f(s[2 * u]);
      const float p1 = __builtin_amdgcn_exp2f(s[2 * u + 1]);
      ls += p0 + p1;
      pk[u] = __builtin_bit_cast(int, __builtin_amdgcn_cvt_pkrtz(p0, p1));
    }
    // P C-layout -> B-layout: one permlane32_swap yields both [lo,lo] and
    // [hi,hi] words (R13-verified).
    int p0w = pk[0], p2w = pk[2];  plswap(p0w, p2w);
    int p1w = pk[1], p3w = pk[3];  plswap(p1w, p3w);
    int p4w = pk[4], p6w = pk[6];  plswap(p4w, p6w);
    int p5w = pk[5], p7w = pk[7];  plswap(p5w, p7w);
    int4v B0i, B1i;
    B0i[0] = p0w; B0i[1] = p1w; B0i[2] = p2w; B0i[3] = p3w;
    B1i[0] = p4w; B1i[1] = p5w; B1i[2] = p6w; B1i[3] = p7w;
    const half8 P0 = __builtin_bit_cast(half8, B0i);
    const half8 P1 = __builtin_bit_cast(half8, B1i);
    acc0 = __builtin_amdgcn_mfma_f32_32x32x16_f16(v00, P0, acc0, 0, 0, 0);
    acc0 = __builtin_amdgcn_mfma_f32_32x32x16_f16(v01, P1, acc0, 0, 0, 0);
    acc1 = __builtin_amdgcn_mfma_f32_32x32x16_f16(v10, P0, acc1, 0, 0, 0);
    acc1 = __builtin_amdgcn_mfma_f32_32x32x16_f16(v11, P1, acc1, 0, 0, 0);
    kcur = knext;
  }

  // ---- cross-wave merge in own region, then write partials (undivided).
  float* Ow = SMf[wave];                 // 64 x 17 f32 (stride 17: bank-free)
  float* Lw = SMf[wave] + 1100;          // 32 f32
  ls += __shfl_xor(ls, 32, 64);
  if (hi == 0) Lw[q31] = ls;
#pragma unroll
  for (int r2 = 0; r2 < 16; ++r2) Ow[lane * 17 + r2] = acc0[r2];
  __syncthreads();
  float ltot = 0.f;
#pragma unroll
  for (int w = 0; w < 4; ++w) ltot += SMf[w][1100 + q31];
  float* Op = Opart + (size_t)tile * 2048;
  if (wave == 0 && hi == 0) Lpart[tile * 32 + q31] = ltot;
#pragma unroll
  for (int r2 = 0; r2 < 16; ++r2) {
    float osum = 0.f;
#pragma unroll
    for (int w = 0; w < 4; ++w) osum += SMf[w][lane * 17 + r2];
    const int c = (r2 & 3) + 8 * (r2 >> 2) + 4 * hi;
    Op[c * 32 + q31] = osum;
  }
  __syncthreads();
#pragma unroll
  for (int r2 = 0; r2 < 16; ++r2) Ow[lane * 17 + r2] = acc1[r2];
  __syncthreads();
#pragma unroll
  for (int r2 = 0; r2 < 16; ++r2) {
    float osum = 0.f;
#pragma unroll
    for (int w = 0; w < 4; ++w) osum += SMf[w][lane * 17 + r2];
    const int c = 32 + (r2 & 3) + 8 * (r2 >> 2) + 4 * hi;
    Op[c * 32 + q31] = osum;
  }
}

// ---------------------------------------------------------------- k_merge
// 576 blocks (b, jt): out = gm*(O0+O1)/(l0+l1) + x.
__global__ __launch_bounds__(256) void k_merge(const float* __restrict__ Opart,
                                               const float* __restrict__ Lpart,
                                               const float* __restrict__ x,
                                               const float* __restrict__ gamma,
                                               float* __restrict__ out) {
  __shared__ float Ls[32];
  const int t2 = blockIdx.x;              // 0..575
  const int b = t2 / 288, jt = t2 % 288;
  const int jb = jt * 32;
  const int tile0 = b * 576 + jt * 2;
  const float gm = gamma[0];
  const int t = threadIdx.x;
  if (t < 32) Ls[t] = Lpart[tile0 * 32 + t] + Lpart[(tile0 + 1) * 32 + t];
  __syncthreads();
  const float* O0 = Opart + (size_t)tile0 * 2048;
  const float* O1 = O0 + 2048;
  const float* xb = x + (size_t)b * N_C * N_PIX;
  float* ob = out + (size_t)b * N_C * N_PIX;
#pragma unroll
  for (int k = 0; k < 8; ++k) {
    const int idx = t + 256 * k;
    const int c = idx >> 5, q = idx & 31;
    const size_t gi = (size_t)c * N_PIX + jb + q;
    ob[gi] = gm * (O0[idx] + O1[idx]) / Ls[q] + xb[gi];
  }
}

// ---------------------------------------------------------------- launch
extern "C" void kernel_launch(void* const* d_in, const int* in_sizes, int n_in,
                              void* d_out, int out_size, void* d_ws, size_t ws_size,
                              hipStream_t stream) {
  const float* x     = (const float*)d_in[0];
  const float* Wq    = (const float*)d_in[1];
  const float* bq    = (const float*)d_in[2];
  const float* Wk    = (const float*)d_in[3];
  const float* bk    = (const float*)d_in[4];
  const float* Wv    = (const float*)d_in[5];
  const float* bv    = (const float*)d_in[6];
  const float* gamma = (const float*)d_in[7];
  float* out = (float*)d_out;

  char* ws = (char*)d_ws;
  float*    sig   = (float*)ws;                       // 4 floats
  unsigned* maxKu = (unsigned*)(ws + 16);             // 2 uints
  _Float16* K16   = (_Float16*)(ws + 10752);          // 294912 B
  _Float16* Q16   = (_Float16*)(ws + 10752 + 294912); // 294912 B
  _Float16* VT16  = (_Float16*)(ws + 10752 + 2 * 294912); // 2359296 B
  float*    Opart = (float*)(ws + 2960384);           // 1152*2048*4 = 9437184 B
  float*    Lpart = (float*)(ws + 2960384 + 9437184); // 1152*32*4 = 147456 B

  hipLaunchKernelGGL(k_sigma, dim3(3), dim3(64), 0, stream, Wq, Wk, Wv, sig, maxKu);
  hipLaunchKernelGGL(k_fgh, dim3(288), dim3(256), 0, stream,
                     x, Wq, bq, Wk, bk, Wv, bv, sig, K16, Q16, VT16, maxKu);
  hipLaunchKernelGGL(k_attn, dim3(1152), dim3(256), 0, stream, K16, Q16, VT16, maxKu, Opart, Lpart);
  hipLaunchKernelGGL(k_merge, dim3(576), dim3(256), 0, stream, Opart, Lpart, x, gamma, out);
}

// Round 3
// 199.229 us; speedup vs baseline: 1.0069x; 1.0069x over previous
//
#include <hip/hip_runtime.h>

// SelfAttention (SAGAN-style) on MI355X.
// B=2, C=64, C8=8, H=W=96, N=9216.  out = gamma * Attn(g,f,h) + x
//   K = f = (Wq/sq) x + bq   (pre-scaled by log2e; softmax in exp2 domain)
//   Q = g = (Wk/sk) x + bk
//   V = h = (Wv/sv) x + bv
// softmax over keys i; head_dim 8 (zero-padded), dv=64.
//
// R15: register double-buffer for V. R14 evidence: occupancy rose 28->43%
// (LDS-free worked) but dur 64.8->99.1 with MfmaUtil AND VALUBusy halved ->
// per-wave stall: V was issued and consumed in the SAME round (~25 instr
// apart) while the 32-row scattered load takes 100s of cycles. R13 hid this
// with a full-round LDS double-buffer. Fix: prefetch round r+1's V (4x
// dwordx4) and K (1x dwordx4) into named registers at round r top; compute
// round r from registers loaded a full round earlier. Steady state = 10
// outstanding loads, compiler waits at vmcnt(5) — R13's pipeline depth with
// zero LDS/barriers in the loop. +16 VGPR (~70 total < 102 cap @ 5 w/SIMD).
// Last-round prefetch overruns <=240B into Opart (allocated, never used).
// Numerics unchanged (M = |Q|*max|K'| - 12, f16 P, f32 lsum).

#define N_PIX 9216
#define N_B   2
#define N_C   64

typedef _Float16 half8  __attribute__((ext_vector_type(8)));
typedef float    float4v __attribute__((ext_vector_type(4)));
typedef float    float16v __attribute__((ext_vector_type(16)));
typedef int      int4v  __attribute__((ext_vector_type(4)));

#define LOG2E 1.44269504088896340736f
#define EXP_SHIFT 12.0f

// ---------------------------------------------------------------- k_sigma
__global__ __launch_bounds__(64) void k_sigma(const float* __restrict__ Wq,
                                              const float* __restrict__ Wk,
                                              const float* __restrict__ Wv,
                                              float* __restrict__ sig,
                                              unsigned* __restrict__ maxKu) {
  __shared__ float G8[8][8];
  __shared__ float Wl[64 * 64];
  __shared__ _Float16 Wh[64 * 80];
  __shared__ _Float16 Gh[64 * 80];
  const int t = threadIdx.x;
  const int mat = blockIdx.x;
  if (mat == 0 && t < 2) maxKu[t] = 0u;
  if (mat < 2) {
    const float* W = (mat == 0) ? Wq : Wk;
    const int i = t >> 3, j = t & 7;
    float g = 0.f;
    for (int c = 0; c < 64; ++c) g += W[i * 64 + c] * W[j * 64 + c];
    G8[i][j] = g;
    __syncthreads();
    const int L = t & 7;
    float G0[8], Gr[8];
    for (int k = 0; k < 8; ++k) { G0[k] = G8[L][k]; Gr[k] = G0[k]; }
    for (int it = 0; it < 8; ++it) {
      float g2[8] = {0, 0, 0, 0, 0, 0, 0, 0};
      for (int k = 0; k < 8; ++k) {
        float gik = Gr[k];
        for (int jj = 0; jj < 8; ++jj) g2[jj] += gik * __shfl(Gr[jj], k, 64);
      }
      float mx = 0.f;
      for (int jj = 0; jj < 8; ++jj) mx = fmaxf(mx, fabsf(g2[jj]));
      for (int d = 1; d < 8; d <<= 1) mx = fmaxf(mx, __shfl_xor(mx, d, 64));
      float r = 1.f / mx;
      for (int jj = 0; jj < 8; ++jj) Gr[jj] = g2[jj] * r;
    }
    float u = 0.f;
    for (int jj = 0; jj < 8; ++jj) u += Gr[jj];
    float y = 0.f;
    for (int k = 0; k < 8; ++k) y += G0[k] * __shfl(u, k, 64);
    float nu = u * y, de = u * u;
    for (int d = 1; d < 8; d <<= 1) { nu += __shfl_xor(nu, d, 64); de += __shfl_xor(de, d, 64); }
    if (t == 0) sig[mat] = sqrtf(nu / de);
  } else {
    for (int idx = t; idx < 4096; idx += 64) Wl[idx] = Wv[idx];
    __syncthreads();
    for (int idx = t; idx < 4096; idx += 64) Wh[(idx >> 6) * 80 + (idx & 63)] = (_Float16)Wl[idx];
    __syncthreads();
    const int lane15 = t & 15, quad = t >> 4;
    half8 fr[4][2];
    for (int rb = 0; rb < 4; ++rb)
      for (int kc = 0; kc < 2; ++kc)
        fr[rb][kc] = *(const half8*)&Wh[(lane15 + 16 * rb) * 80 + 32 * kc + 8 * quad];
    float4v D[4][4];
    for (int mb = 0; mb < 4; ++mb) for (int nb = 0; nb < 4; ++nb) D[mb][nb] = (float4v){0.f, 0.f, 0.f, 0.f};
    for (int kc = 0; kc < 2; ++kc)
      for (int mb = 0; mb < 4; ++mb)
        for (int nb = 0; nb < 4; ++nb)
          D[mb][nb] = __builtin_amdgcn_mfma_f32_16x16x32_f16(fr[mb][kc], fr[nb][kc], D[mb][nb], 0, 0, 0);
    for (int it = 0; it < 8; ++it) {
      float mx = 0.f;
      for (int mb = 0; mb < 4; ++mb) for (int nb = 0; nb < 4; ++nb) for (int r = 0; r < 4; ++r)
        mx = fmaxf(mx, fabsf(D[mb][nb][r]));
      for (int d = 1; d < 64; d <<= 1) mx = fmaxf(mx, __shfl_xor(mx, d, 64));
      float rs = 1.f / mx;
      for (int mb = 0; mb < 4; ++mb) for (int nb = 0; nb < 4; ++nb) for (int r = 0; r < 4; ++r)
        Gh[(4 * quad + r + 16 * mb) * 80 + lane15 + 16 * nb] = (_Float16)(D[mb][nb][r] * rs);
      __syncthreads();
      if (it == 7) break;
      for (int rb = 0; rb < 4; ++rb)
        for (int kc = 0; kc < 2; ++kc)
          fr[rb][kc] = *(const half8*)&Gh[(lane15 + 16 * rb) * 80 + 32 * kc + 8 * quad];
      for (int mb = 0; mb < 4; ++mb) for (int nb = 0; nb < 4; ++nb) D[mb][nb] = (float4v){0.f, 0.f, 0.f, 0.f};
      for (int kc = 0; kc < 2; ++kc)
        for (int mb = 0; mb < 4; ++mb)
          for (int nb = 0; nb < 4; ++nb)
            D[mb][nb] = __builtin_amdgcn_mfma_f32_16x16x32_f16(fr[mb][kc], fr[nb][kc], D[mb][nb], 0, 0, 0);
      __syncthreads();
    }
    float u = 0.f;
    for (int c = 0; c < 64; ++c) u += (float)Gh[t * 80 + c];
    float z = 0.f;
    for (int i2 = 0; i2 < 64; ++i2) z += Wl[i2 * 64 + t] * __shfl(u, i2, 64);
    float nu = z * z, de = u * u;
    for (int d = 1; d < 64; d <<= 1) { nu += __shfl_xor(nu, d, 64); de += __shfl_xor(de, d, 64); }
    if (t == 0) sig[2] = sqrtf(nu / de);
  }
}

// ---------------------------------------------------------------- k_fgh
__global__ __launch_bounds__(256) void k_fgh(const float* __restrict__ x,
                                             const float* __restrict__ Wq, const float* __restrict__ bq,
                                             const float* __restrict__ Wk, const float* __restrict__ bk,
                                             const float* __restrict__ Wv, const float* __restrict__ bv,
                                             const float* __restrict__ sig,
                                             _Float16* __restrict__ K16,
                                             _Float16* __restrict__ Q16,
                                             _Float16* __restrict__ VT16,
                                             unsigned* __restrict__ maxKu) {
  __shared__ _Float16 Wsh[80 * 64];
  __shared__ float bsh[80];
  const int t = threadIdx.x;
  const float iq = LOG2E / sig[0], ik = 1.0f / sig[1], iv = 1.0f / sig[2];
  for (int idx = t; idx < 80 * 64; idx += 256) {
    const int m = idx >> 6, c = idx & 63;
    float v;
    if (m < 8)       v = Wq[m * 64 + c] * iq;
    else if (m < 16) v = Wk[(m - 8) * 64 + c] * ik;
    else             v = Wv[(m - 16) * 64 + c] * iv;
    Wsh[idx] = (_Float16)v;
  }
  if (t < 80) {
    float v;
    if (t < 8)       v = bq[t] * LOG2E;
    else if (t < 16) v = bk[t - 8];
    else             v = bv[t - 16];
    bsh[t] = v;
  }
  __syncthreads();
  const int wave = t >> 6;
  const int lane = t & 63;
  const int lane15 = lane & 15, quad = lane >> 4;
  const int tile = blockIdx.x * 4 + wave;
  const int b = tile / 576;
  const int n = (tile % 576) * 16 + lane15;
  half8 wf[5][2];
  for (int mb = 0; mb < 5; ++mb)
    for (int kc = 0; kc < 2; ++kc)
      wf[mb][kc] = *(const half8*)&Wsh[(lane15 + 16 * mb) * 64 + 32 * kc + 8 * quad];
  float4v acc[5];
  for (int mb = 0; mb < 5; ++mb) acc[mb] = *(const float4v*)&bsh[16 * mb + 4 * quad];
  const float* xb = x + (size_t)b * N_C * N_PIX;
  for (int kc = 0; kc < 2; ++kc) {
    half8 bf;
    for (int j = 0; j < 8; ++j)
      bf[j] = (_Float16)xb[(size_t)(32 * kc + 8 * quad + j) * N_PIX + n];
    for (int mb = 0; mb < 5; ++mb)
      acc[mb] = __builtin_amdgcn_mfma_f32_16x16x32_f16(wf[mb][kc], bf, acc[mb], 0, 0, 0);
  }
  {
    _Float16* dstK = K16 + ((size_t)b * N_PIX + n) * 8;
    _Float16* dstQ = Q16 + ((size_t)b * N_PIX + n) * 8;
    for (int r = 0; r < 4; ++r) {
      const int m = 4 * quad + r;
      const _Float16 v = (_Float16)acc[0][r];
      if (m < 8) dstK[m] = v; else dstQ[m - 8] = v;
    }
  }
  for (int mb = 1; mb < 5; ++mb)
    for (int r = 0; r < 4; ++r) {
      const int c = 4 * quad + r + 16 * (mb - 1);
      VT16[((size_t)b * N_C + c) * N_PIX + n] = (_Float16)acc[mb][r];
    }
  float sq = 0.f;
  if (quad < 2)
    for (int r = 0; r < 4; ++r) sq += acc[0][r] * acc[0][r];
  sq += __shfl_xor(sq, 16, 64);
  for (int d = 1; d < 64; d <<= 1) sq = fmaxf(sq, __shfl_xor(sq, d, 64));
  if (lane == 0) atomicMax(&maxKu[b], __float_as_uint(sq));
}

// ---------------------------------------------------------------- k_attn
// 1152 blocks: tile = b*576 + jt*2 + h; block covers keys [4608h, +4608),
// 36 rounds of 128 keys (wave w owns 32). Everything in registers:
//   K: per-lane dwordx4, double-buffered (issued 1 round ahead).
//   V: 4x per-lane dwordx4, double-buffered (issued 1 round ahead) ->
//      full-round issue->use distance, steady state 10 outstanding, vmcnt(5).
// LDS only for the epilogue cross-wave merge: float SM[4][1152] = 18432 B.

// v_permlane32_swap_b32: a' = [a.lo, b.lo], b' = [a.hi, b.hi]
__device__ __forceinline__ void plswap(int& a, int& b) {
  asm("v_permlane32_swap_b32 %0, %1" : "+v"(a), "+v"(b));
}

__global__ __launch_bounds__(256, 5) void k_attn(const _Float16* __restrict__ K16,
                                                 const _Float16* __restrict__ Q16,
                                                 const _Float16* __restrict__ VT16,
                                                 const unsigned* __restrict__ maxKu,
                                                 float* __restrict__ Opart,
                                                 float* __restrict__ Lpart) {
  __shared__ float SMf[4][1152];          // 18432 B, epilogue only
  const int wave = threadIdx.x >> 6;
  const int lane = threadIdx.x & 63;
  const int q31 = lane & 31, hi = lane >> 5;
  const int tile = blockIdx.x;            // 0..1151
  const int b = tile / 576;
  const int rm = tile % 576;
  const int jb = (rm >> 1) * 32;
  const int h = rm & 1;
  const int kh = h * (N_PIX / 2);         // this block's key range base
  const _Float16* Kb = K16 + (size_t)b * N_PIX * 8;
  const _Float16* Vb = VT16 + (size_t)b * N_C * N_PIX;

  // Q B-frag: n=q31, k=8*hi+j; hi=0 lanes real (dims 0-7), hi=1 zero.
  half8 qf = {};
  if (hi == 0) qf = *(const half8*)(Q16 + ((size_t)b * N_PIX + jb + q31) * 8);
  const float maxK = sqrtf(__uint_as_float(maxKu[b]));
  float nq = 0.f;
#pragma unroll
  for (int j = 0; j < 8; ++j) nq += (float)qf[j] * (float)qf[j];
  nq += __shfl_xor(nq, 32, 64);
  const float M = sqrtf(nq) * maxK - EXP_SHIFT;
  float16v sinit;
#pragma unroll
  for (int r2 = 0; r2 < 16; ++r2) sinit[r2] = -M;

  float16v acc0 = {}, acc1 = {};
  float ls = 0.f;

  const int i0 = kh + 32 * wave;          // first key of this wave's stream
  // 32-bit element offsets against uniform bases (saddr + voffset form).
  const int okf = (i0 + q31) * 8;         // K: += 1024/round
  const int ov0 = q31 * N_PIX + i0 + 8 * hi;        // V ch q31:   += 128/round
  const int ov1 = ov0 + 32 * N_PIX;                 // V ch 32+q31

  // Round-0 operands (consumed in round 0, loaded here = prologue).
  int4v kcur = *(const int4v*)(Kb + okf);
  half8 v00c = *(const half8*)(Vb + ov0);
  half8 v01c = *(const half8*)(Vb + ov0 + 16);
  half8 v10c = *(const half8*)(Vb + ov1);
  half8 v11c = *(const half8*)(Vb + ov1 + 16);

#pragma unroll 1
  for (int r = 0; r < 36; ++r) {
    const int kn = 128 * (r + 1);
    // ---- prefetch round r+1 (r=35: reads <=240B past VT16 into Opart /
    // past K16 into Q16 — allocated, never consumed).
    half8 v00n = *(const half8*)(Vb + ov0 + kn);
    half8 v01n = *(const half8*)(Vb + ov0 + kn + 16);
    half8 v10n = *(const half8*)(Vb + ov1 + kn);
    half8 v11n = *(const half8*)(Vb + ov1 + kn + 16);
    int4v knext = *(const int4v*)(Kb + okf + (r + 1) * 1024);
    // ---- compute round r from registers loaded one round ago.
    // K A-frag: m=key=q31, k=8*hi+j; hi=1 lanes must be ZERO (dims 8-15).
    int4v kcz;
    kcz[0] = hi ? 0 : kcur[0];
    kcz[1] = hi ? 0 : kcur[1];
    kcz[2] = hi ? 0 : kcur[2];
    kcz[3] = hi ? 0 : kcur[3];
    const half8 kf = __builtin_bit_cast(half8, kcz);
    float16v s = __builtin_amdgcn_mfma_f32_32x32x16_f16(kf, qf, sinit, 0, 0, 0);
    int pk[8];
#pragma unroll
    for (int u = 0; u < 8; ++u) {
      const float p0 = __builtin_amdgcn_exp2f(s[2 * u]);
      const float p1 = __builtin_amdgcn_exp2f(s[2 * u + 1]);
      ls += p0 + p1;
      pk[u] = __builtin_bit_cast(int, __builtin_amdgcn_cvt_pkrtz(p0, p1));
    }
    // P C-layout -> B-layout: one permlane32_swap yields both [lo,lo] and
    // [hi,hi] words (R13-verified).
    int p0w = pk[0], p2w = pk[2];  plswap(p0w, p2w);
    int p1w = pk[1], p3w = pk[3];  plswap(p1w, p3w);
    int p4w = pk[4], p6w = pk[6];  plswap(p4w, p6w);
    int p5w = pk[5], p7w = pk[7];  plswap(p5w, p7w);
    int4v B0i, B1i;
    B0i[0] = p0w; B0i[1] = p1w; B0i[2] = p2w; B0i[3] = p3w;
    B1i[0] = p4w; B1i[1] = p5w; B1i[2] = p6w; B1i[3] = p7w;
    const half8 P0 = __builtin_bit_cast(half8, B0i);
    const half8 P1 = __builtin_bit_cast(half8, B1i);
    acc0 = __builtin_amdgcn_mfma_f32_32x32x16_f16(v00c, P0, acc0, 0, 0, 0);
    acc0 = __builtin_amdgcn_mfma_f32_32x32x16_f16(v01c, P1, acc0, 0, 0, 0);
    acc1 = __builtin_amdgcn_mfma_f32_32x32x16_f16(v10c, P0, acc1, 0, 0, 0);
    acc1 = __builtin_amdgcn_mfma_f32_32x32x16_f16(v11c, P1, acc1, 0, 0, 0);
    // ---- rotate buffers.
    kcur = knext;
    v00c = v00n; v01c = v01n; v10c = v10n; v11c = v11n;
  }

  // ---- cross-wave merge in own region, then write partials (undivided).
  float* Ow = SMf[wave];                 // 64 x 17 f32 (stride 17: bank-free)
  float* Lw = SMf[wave] + 1100;          // 32 f32
  ls += __shfl_xor(ls, 32, 64);
  if (hi == 0) Lw[q31] = ls;
#pragma unroll
  for (int r2 = 0; r2 < 16; ++r2) Ow[lane * 17 + r2] = acc0[r2];
  __syncthreads();
  float ltot = 0.f;
#pragma unroll
  for (int w = 0; w < 4; ++w) ltot += SMf[w][1100 + q31];
  float* Op = Opart + (size_t)tile * 2048;
  if (wave == 0 && hi == 0) Lpart[tile * 32 + q31] = ltot;
#pragma unroll
  for (int r2 = 0; r2 < 16; ++r2) {
    float osum = 0.f;
#pragma unroll
    for (int w = 0; w < 4; ++w) osum += SMf[w][lane * 17 + r2];
    const int c = (r2 & 3) + 8 * (r2 >> 2) + 4 * hi;
    Op[c * 32 + q31] = osum;
  }
  __syncthreads();
#pragma unroll
  for (int r2 = 0; r2 < 16; ++r2) Ow[lane * 17 + r2] = acc1[r2];
  __syncthreads();
#pragma unroll
  for (int r2 = 0; r2 < 16; ++r2) {
    float osum = 0.f;
#pragma unroll
    for (int w = 0; w < 4; ++w) osum += SMf[w][lane * 17 + r2];
    const int c = 32 + (r2 & 3) + 8 * (r2 >> 2) + 4 * hi;
    Op[c * 32 + q31] = osum;
  }
}

// ---------------------------------------------------------------- k_merge
// 576 blocks (b, jt): out = gm*(O0+O1)/(l0+l1) + x.
__global__ __launch_bounds__(256) void k_merge(const float* __restrict__ Opart,
                                               const float* __restrict__ Lpart,
                                               const float* __restrict__ x,
                                               const float* __restrict__ gamma,
                                               float* __restrict__ out) {
  __shared__ float Ls[32];
  const int t2 = blockIdx.x;              // 0..575
  const int b = t2 / 288, jt = t2 % 288;
  const int jb = jt * 32;
  const int tile0 = b * 576 + jt * 2;
  const float gm = gamma[0];
  const int t = threadIdx.x;
  if (t < 32) Ls[t] = Lpart[tile0 * 32 + t] + Lpart[(tile0 + 1) * 32 + t];
  __syncthreads();
  const float* O0 = Opart + (size_t)tile0 * 2048;
  const float* O1 = O0 + 2048;
  const float* xb = x + (size_t)b * N_C * N_PIX;
  float* ob = out + (size_t)b * N_C * N_PIX;
#pragma unroll
  for (int k = 0; k < 8; ++k) {
    const int idx = t + 256 * k;
    const int c = idx >> 5, q = idx & 31;
    const size_t gi = (size_t)c * N_PIX + jb + q;
    ob[gi] = gm * (O0[idx] + O1[idx]) / Ls[q] + xb[gi];
  }
}

// ---------------------------------------------------------------- launch
extern "C" void kernel_launch(void* const* d_in, const int* in_sizes, int n_in,
                              void* d_out, int out_size, void* d_ws, size_t ws_size,
                              hipStream_t stream) {
  const float* x     = (const float*)d_in[0];
  const float* Wq    = (const float*)d_in[1];
  const float* bq    = (const float*)d_in[2];
  const float* Wk    = (const float*)d_in[3];
  const float* bk    = (const float*)d_in[4];
  const float* Wv    = (const float*)d_in[5];
  const float* bv    = (const float*)d_in[6];
  const float* gamma = (const float*)d_in[7];
  float* out = (float*)d_out;

  char* ws = (char*)d_ws;
  float*    sig   = (float*)ws;                       // 4 floats
  unsigned* maxKu = (unsigned*)(ws + 16);             // 2 uints
  _Float16* K16   = (_Float16*)(ws + 10752);          // 294912 B
  _Float16* Q16   = (_Float16*)(ws + 10752 + 294912); // 294912 B
  _Float16* VT16  = (_Float16*)(ws + 10752 + 2 * 294912); // 2359296 B
  float*    Opart = (float*)(ws + 2960384);           // 1152*2048*4 = 9437184 B
  float*    Lpart = (float*)(ws + 2960384 + 9437184); // 1152*32*4 = 147456 B

  hipLaunchKernelGGL(k_sigma, dim3(3), dim3(64), 0, stream, Wq, Wk, Wv, sig, maxKu);
  hipLaunchKernelGGL(k_fgh, dim3(288), dim3(256), 0, stream,
                     x, Wq, bq, Wk, bk, Wv, bv, sig, K16, Q16, VT16, maxKu);
  hipLaunchKernelGGL(k_attn, dim3(1152), dim3(256), 0, stream, K16, Q16, VT16, maxKu, Opart, Lpart);
  hipLaunchKernelGGL(k_merge, dim3(576), dim3(256), 0, stream, Opart, Lpart, x, gamma, out);
}

// Round 6
// 161.415 us; speedup vs baseline: 1.2428x; 1.2343x over previous
//
#include <hip/hip_runtime.h>

// SelfAttention (SAGAN-style) on MI355X.
// B=2, C=64, C8=8, H=W=96, N=9216.  out = gamma * Attn(g,f,h) + x
//   K = f = (Wq/sq) x + bq   (pre-scaled by log2e; softmax in exp2 domain)
//   Q = g = (Wk/sk) x + bk
//   V = h = (Wv/sv) x + bv
// softmax over keys i; head_dim 8 (zero-padded), dv=64.
//
// R18: 3-wave blocks kill the tail with R13's proven machinery. R16/R17
// (register pipelines) gave no data (crash/container failure) -> re-anchor.
// R13 evidence: LDS 32768 x 5 = EXACTLY 163840 B (full pool) -> exact-fit
// allocation fails, residency stuck at 4 blocks/CU, and occupancy 28% =
// (16w*T + 2w*T)/2T: HALF the time is the 128-block tail. Fix: 192-thread
// blocks (3 waves), per-wave LDS unchanged (4096 halves dbuf V) -> block
// LDS 24576 B -> 6 blocks/CU (147456 B, 16KB slack). Grid 1152 < 1536 cap
// -> ALL blocks co-resident, no tail, flat 13.5 waves/CU vs R13's avg ~9.
// Rounds 36->48 (96 keys/round/block); total wave-rounds identical.
// Loop body byte-identical to R13 (gload16 + vmcnt(5) + permlane swap,
// clamped last prefetch -> zero OOB). Merge width 4->3 waves.
// Numerics unchanged (M = |Q|*max|K'| - 12, f16 P, f32 lsum).

#define N_PIX 9216
#define N_B   2
#define N_C   64

typedef _Float16 half8  __attribute__((ext_vector_type(8)));
typedef float    float4v __attribute__((ext_vector_type(4)));
typedef float    float16v __attribute__((ext_vector_type(16)));
typedef int      int4v  __attribute__((ext_vector_type(4)));

#define LOG2E 1.44269504088896340736f
#define EXP_SHIFT 12.0f

// ---------------------------------------------------------------- k_sigma
__global__ __launch_bounds__(64) void k_sigma(const float* __restrict__ Wq,
                                              const float* __restrict__ Wk,
                                              const float* __restrict__ Wv,
                                              float* __restrict__ sig,
                                              unsigned* __restrict__ maxKu) {
  __shared__ float G8[8][8];
  __shared__ float Wl[64 * 64];
  __shared__ _Float16 Wh[64 * 80];
  __shared__ _Float16 Gh[64 * 80];
  const int t = threadIdx.x;
  const int mat = blockIdx.x;
  if (mat == 0 && t < 2) maxKu[t] = 0u;
  if (mat < 2) {
    const float* W = (mat == 0) ? Wq : Wk;
    const int i = t >> 3, j = t & 7;
    float g = 0.f;
    for (int c = 0; c < 64; ++c) g += W[i * 64 + c] * W[j * 64 + c];
    G8[i][j] = g;
    __syncthreads();
    const int L = t & 7;
    float G0[8], Gr[8];
    for (int k = 0; k < 8; ++k) { G0[k] = G8[L][k]; Gr[k] = G0[k]; }
    for (int it = 0; it < 8; ++it) {
      float g2[8] = {0, 0, 0, 0, 0, 0, 0, 0};
      for (int k = 0; k < 8; ++k) {
        float gik = Gr[k];
        for (int jj = 0; jj < 8; ++jj) g2[jj] += gik * __shfl(Gr[jj], k, 64);
      }
      float mx = 0.f;
      for (int jj = 0; jj < 8; ++jj) mx = fmaxf(mx, fabsf(g2[jj]));
      for (int d = 1; d < 8; d <<= 1) mx = fmaxf(mx, __shfl_xor(mx, d, 64));
      float r = 1.f / mx;
      for (int jj = 0; jj < 8; ++jj) Gr[jj] = g2[jj] * r;
    }
    float u = 0.f;
    for (int jj = 0; jj < 8; ++jj) u += Gr[jj];
    float y = 0.f;
    for (int k = 0; k < 8; ++k) y += G0[k] * __shfl(u, k, 64);
    float nu = u * y, de = u * u;
    for (int d = 1; d < 8; d <<= 1) { nu += __shfl_xor(nu, d, 64); de += __shfl_xor(de, d, 64); }
    if (t == 0) sig[mat] = sqrtf(nu / de);
  } else {
    for (int idx = t; idx < 4096; idx += 64) Wl[idx] = Wv[idx];
    __syncthreads();
    for (int idx = t; idx < 4096; idx += 64) Wh[(idx >> 6) * 80 + (idx & 63)] = (_Float16)Wl[idx];
    __syncthreads();
    const int lane15 = t & 15, quad = t >> 4;
    half8 fr[4][2];
    for (int rb = 0; rb < 4; ++rb)
      for (int kc = 0; kc < 2; ++kc)
        fr[rb][kc] = *(const half8*)&Wh[(lane15 + 16 * rb) * 80 + 32 * kc + 8 * quad];
    float4v D[4][4];
    for (int mb = 0; mb < 4; ++mb) for (int nb = 0; nb < 4; ++nb) D[mb][nb] = (float4v){0.f, 0.f, 0.f, 0.f};
    for (int kc = 0; kc < 2; ++kc)
      for (int mb = 0; mb < 4; ++mb)
        for (int nb = 0; nb < 4; ++nb)
          D[mb][nb] = __builtin_amdgcn_mfma_f32_16x16x32_f16(fr[mb][kc], fr[nb][kc], D[mb][nb], 0, 0, 0);
    for (int it = 0; it < 8; ++it) {
      float mx = 0.f;
      for (int mb = 0; mb < 4; ++mb) for (int nb = 0; nb < 4; ++nb) for (int r = 0; r < 4; ++r)
        mx = fmaxf(mx, fabsf(D[mb][nb][r]));
      for (int d = 1; d < 64; d <<= 1) mx = fmaxf(mx, __shfl_xor(mx, d, 64));
      float rs = 1.f / mx;
      for (int mb = 0; mb < 4; ++mb) for (int nb = 0; nb < 4; ++nb) for (int r = 0; r < 4; ++r)
        Gh[(4 * quad + r + 16 * mb) * 80 + lane15 + 16 * nb] = (_Float16)(D[mb][nb][r] * rs);
      __syncthreads();
      if (it == 7) break;
      for (int rb = 0; rb < 4; ++rb)
        for (int kc = 0; kc < 2; ++kc)
          fr[rb][kc] = *(const half8*)&Gh[(lane15 + 16 * rb) * 80 + 32 * kc + 8 * quad];
      for (int mb = 0; mb < 4; ++mb) for (int nb = 0; nb < 4; ++nb) D[mb][nb] = (float4v){0.f, 0.f, 0.f, 0.f};
      for (int kc = 0; kc < 2; ++kc)
        for (int mb = 0; mb < 4; ++mb)
          for (int nb = 0; nb < 4; ++nb)
            D[mb][nb] = __builtin_amdgcn_mfma_f32_16x16x32_f16(fr[mb][kc], fr[nb][kc], D[mb][nb], 0, 0, 0);
      __syncthreads();
    }
    float u = 0.f;
    for (int c = 0; c < 64; ++c) u += (float)Gh[t * 80 + c];
    float z = 0.f;
    for (int i2 = 0; i2 < 64; ++i2) z += Wl[i2 * 64 + t] * __shfl(u, i2, 64);
    float nu = z * z, de = u * u;
    for (int d = 1; d < 64; d <<= 1) { nu += __shfl_xor(nu, d, 64); de += __shfl_xor(de, d, 64); }
    if (t == 0) sig[2] = sqrtf(nu / de);
  }
}

// ---------------------------------------------------------------- k_fgh
__global__ __launch_bounds__(256) void k_fgh(const float* __restrict__ x,
                                             const float* __restrict__ Wq, const float* __restrict__ bq,
                                             const float* __restrict__ Wk, const float* __restrict__ bk,
                                             const float* __restrict__ Wv, const float* __restrict__ bv,
                                             const float* __restrict__ sig,
                                             _Float16* __restrict__ K16,
                                             _Float16* __restrict__ Q16,
                                             _Float16* __restrict__ VT16,
                                             unsigned* __restrict__ maxKu) {
  __shared__ _Float16 Wsh[80 * 64];
  __shared__ float bsh[80];
  const int t = threadIdx.x;
  const float iq = LOG2E / sig[0], ik = 1.0f / sig[1], iv = 1.0f / sig[2];
  for (int idx = t; idx < 80 * 64; idx += 256) {
    const int m = idx >> 6, c = idx & 63;
    float v;
    if (m < 8)       v = Wq[m * 64 + c] * iq;
    else if (m < 16) v = Wk[(m - 8) * 64 + c] * ik;
    else             v = Wv[(m - 16) * 64 + c] * iv;
    Wsh[idx] = (_Float16)v;
  }
  if (t < 80) {
    float v;
    if (t < 8)       v = bq[t] * LOG2E;
    else if (t < 16) v = bk[t - 8];
    else             v = bv[t - 16];
    bsh[t] = v;
  }
  __syncthreads();
  const int wave = t >> 6;
  const int lane = t & 63;
  const int lane15 = lane & 15, quad = lane >> 4;
  const int tile = blockIdx.x * 4 + wave;
  const int b = tile / 576;
  const int n = (tile % 576) * 16 + lane15;
  half8 wf[5][2];
  for (int mb = 0; mb < 5; ++mb)
    for (int kc = 0; kc < 2; ++kc)
      wf[mb][kc] = *(const half8*)&Wsh[(lane15 + 16 * mb) * 64 + 32 * kc + 8 * quad];
  float4v acc[5];
  for (int mb = 0; mb < 5; ++mb) acc[mb] = *(const float4v*)&bsh[16 * mb + 4 * quad];
  const float* xb = x + (size_t)b * N_C * N_PIX;
  for (int kc = 0; kc < 2; ++kc) {
    half8 bf;
    for (int j = 0; j < 8; ++j)
      bf[j] = (_Float16)xb[(size_t)(32 * kc + 8 * quad + j) * N_PIX + n];
    for (int mb = 0; mb < 5; ++mb)
      acc[mb] = __builtin_amdgcn_mfma_f32_16x16x32_f16(wf[mb][kc], bf, acc[mb], 0, 0, 0);
  }
  {
    _Float16* dstK = K16 + ((size_t)b * N_PIX + n) * 8;
    _Float16* dstQ = Q16 + ((size_t)b * N_PIX + n) * 8;
    for (int r = 0; r < 4; ++r) {
      const int m = 4 * quad + r;
      const _Float16 v = (_Float16)acc[0][r];
      if (m < 8) dstK[m] = v; else dstQ[m - 8] = v;
    }
  }
  for (int mb = 1; mb < 5; ++mb)
    for (int r = 0; r < 4; ++r) {
      const int c = 4 * quad + r + 16 * (mb - 1);
      VT16[((size_t)b * N_C + c) * N_PIX + n] = (_Float16)acc[mb][r];
    }
  float sq = 0.f;
  if (quad < 2)
    for (int r = 0; r < 4; ++r) sq += acc[0][r] * acc[0][r];
  sq += __shfl_xor(sq, 16, 64);
  for (int d = 1; d < 64; d <<= 1) sq = fmaxf(sq, __shfl_xor(sq, d, 64));
  if (lane == 0) atomicMax(&maxKu[b], __float_as_uint(sq));
}

// ---------------------------------------------------------------- k_attn
// 1152 blocks x 192 threads (3 waves): tile = b*576 + jt*2 + h; block covers
// keys [4608h, +4608), 48 rounds of 96 keys (wave w owns 32). K in registers
// (double-buffered); V double-buffered in LDS per wave (4096 halves,
// swizzled g^((c>>1)&3)). Block LDS 24576 B -> 6 blocks/CU -> all 1152
// resident (cap 1536), no tail.

__device__ __forceinline__ void gload16(const _Float16* g, _Float16* l) {
  __builtin_amdgcn_global_load_lds(
      (const __attribute__((address_space(1))) void*)g,
      (__attribute__((address_space(3))) void*)l, 16, 0, 0);
}
#define VMWAIT5() asm volatile("s_waitcnt vmcnt(5)" ::: "memory")

// v_permlane32_swap_b32: a' = [a.lo, b.lo], b' = [a.hi, b.hi]
__device__ __forceinline__ void plswap(int& a, int& b) {
  asm("v_permlane32_swap_b32 %0, %1" : "+v"(a), "+v"(b));
}

__global__ __launch_bounds__(192, 4) void k_attn(const _Float16* __restrict__ K16,
                                                 const _Float16* __restrict__ Q16,
                                                 const _Float16* __restrict__ VT16,
                                                 const unsigned* __restrict__ maxKu,
                                                 float* __restrict__ Opart,
                                                 float* __restrict__ Lpart) {
  __shared__ __align__(16) _Float16 SM[3][4096];   // 24576 B -> 6 blocks/CU
  const int wave = threadIdx.x >> 6;      // 0..2
  const int lane = threadIdx.x & 63;
  const int q31 = lane & 31, hi = lane >> 5;
  const int tile = blockIdx.x;            // 0..1151
  const int b = tile / 576;
  const int rm = tile % 576;
  const int jb = (rm >> 1) * 32;
  const int h = rm & 1;
  const int kh = h * (N_PIX / 2);         // this block's key range base
  const _Float16* Kb = K16 + (size_t)b * N_PIX * 8;
  const _Float16* Vb = VT16 + (size_t)b * N_C * N_PIX;
  _Float16* Rg = SM[wave];
  // V staging: instr i covers channel c=16i+cl, cl=lane>>2, LDS granule
  // kk=lane&3, source granule = kk ^ ((cl>>1)&3)
  const int cl = lane >> 2, kk = lane & 3;
  const int gsw = (kk ^ ((cl >> 1) & 3)) * 8;
  // read offsets: channel row 32c; granule g at slot g ^ ((c>>1)&3)
  const int vx = (q31 >> 1) & 3;
  const int voff00 = q31 * 32 + ((hi ^ vx) << 3);
  const int voff01 = q31 * 32 + (((2 + hi) ^ vx) << 3);
  const int voff10 = 1024 + voff00;
  const int voff11 = 1024 + voff01;

  // Q B-frag: n=q31, k=8*hi+j; hi=0 lanes real (dims 0-7), hi=1 zero.
  half8 qf = {};
  if (hi == 0) qf = *(const half8*)(Q16 + ((size_t)b * N_PIX + jb + q31) * 8);
  const float maxK = sqrtf(__uint_as_float(maxKu[b]));
  float nq = 0.f;
#pragma unroll
  for (int j = 0; j < 8; ++j) nq += (float)qf[j] * (float)qf[j];
  nq += __shfl_xor(nq, 32, 64);
  const float M = sqrtf(nq) * maxK - EXP_SHIFT;
  float16v sinit;
#pragma unroll
  for (int r2 = 0; r2 < 16; ++r2) sinit[r2] = -M;

  float16v acc0 = {}, acc1 = {};
  float ls = 0.f;

#define STAGEV(SLOT, I0)                                                         \
  {                                                                              \
    const int _i = (I0);                                                         \
    gload16(Vb + (size_t)cl * N_PIX + _i + gsw,        Rg + (SLOT) * 2048);      \
    gload16(Vb + (size_t)(16 + cl) * N_PIX + _i + gsw, Rg + (SLOT) * 2048 + 512);\
    gload16(Vb + (size_t)(32 + cl) * N_PIX + _i + gsw, Rg + (SLOT) * 2048 + 1024);\
    gload16(Vb + (size_t)(48 + cl) * N_PIX + _i + gsw, Rg + (SLOT) * 2048 + 1536);\
  }

  // K base for this wave's key stream; +768 halves (96 keys) per round.
  const _Float16* kpt = Kb + (size_t)(kh + 32 * wave + q31) * 8;
  int4v kcur = *(const int4v*)kpt;        // round 0 K
  STAGEV(0, kh + 32 * wave)

#pragma unroll 1
  for (int r = 0; r < 48; ++r) {
    const int slot = r & 1, nslot = slot ^ 1;
    // prefetch round r+1 (r=47: clamp -> re-load round 47, never consumed)
    const int rn = (r < 47) ? (r + 1) : 47;
    const int i1 = kh + 96 * rn + 32 * wave;
    int4v knext = *(const int4v*)(kpt + (size_t)rn * 768);
    STAGEV(nslot, i1)
    VMWAIT5();
    // K A-frag: m=key=q31, k=8*hi+j; hi=1 lanes must be ZERO (dims 8-15).
    int4v kcz;
    kcz[0] = hi ? 0 : kcur[0];
    kcz[1] = hi ? 0 : kcur[1];
    kcz[2] = hi ? 0 : kcur[2];
    kcz[3] = hi ? 0 : kcur[3];
    const half8 kf = __builtin_bit_cast(half8, kcz);
    float16v s = __builtin_amdgcn_mfma_f32_32x32x16_f16(kf, qf, sinit, 0, 0, 0);
    int pk[8];
#pragma unroll
    for (int u = 0; u < 8; ++u) {
      const float p0 = __builtin_amdgcn_exp2f(s[2 * u]);
      const float p1 = __builtin_amdgcn_exp2f(s[2 * u + 1]);
      ls += p0 + p1;
      pk[u] = __builtin_bit_cast(int, __builtin_amdgcn_cvt_pkrtz(p0, p1));
    }
    // P C-layout -> B-layout: one permlane32_swap yields both [lo,lo] and
    // [hi,hi] words (R13-verified).
    int p0w = pk[0], p2w = pk[2];  plswap(p0w, p2w);
    int p1w = pk[1], p3w = pk[3];  plswap(p1w, p3w);
    int p4w = pk[4], p6w = pk[6];  plswap(p4w, p6w);
    int p5w = pk[5], p7w = pk[7];  plswap(p5w, p7w);
    int4v B0i, B1i;
    B0i[0] = p0w; B0i[1] = p1w; B0i[2] = p2w; B0i[3] = p3w;
    B1i[0] = p4w; B1i[1] = p5w; B1i[2] = p6w; B1i[3] = p7w;
    const half8 P0 = __builtin_bit_cast(half8, B0i);
    const half8 P1 = __builtin_bit_cast(half8, B1i);
    const _Float16* Vs = Rg + slot * 2048;
    const half8 v00 = *(const half8*)&Vs[voff00];
    const half8 v01 = *(const half8*)&Vs[voff01];
    const half8 v10 = *(const half8*)&Vs[voff10];
    const half8 v11 = *(const half8*)&Vs[voff11];
    acc0 = __builtin_amdgcn_mfma_f32_32x32x16_f16(v00, P0, acc0, 0, 0, 0);
    acc0 = __builtin_amdgcn_mfma_f32_32x32x16_f16(v01, P1, acc0, 0, 0, 0);
    acc1 = __builtin_amdgcn_mfma_f32_32x32x16_f16(v10, P0, acc1, 0, 0, 0);
    acc1 = __builtin_amdgcn_mfma_f32_32x32x16_f16(v11, P1, acc1, 0, 0, 0);
    kcur = knext;
  }
#undef STAGEV
  asm volatile("s_waitcnt vmcnt(0)" ::: "memory");  // drain dangling staging

  // ---- cross-wave merge in own region, then write partials (undivided).
  float* Ow = (float*)Rg;                // 64 x 17 f32 (stride 17: bank-free)
  float* Lw = (float*)Rg + 1100;         // 32 f32
  ls += __shfl_xor(ls, 32, 64);
  if (hi == 0) Lw[q31] = ls;
#pragma unroll
  for (int r2 = 0; r2 < 16; ++r2) Ow[lane * 17 + r2] = acc0[r2];
  __syncthreads();
  float ltot = 0.f;
#pragma unroll
  for (int w = 0; w < 3; ++w) ltot += ((const float*)SM[w])[1100 + q31];
  float* Op = Opart + (size_t)tile * 2048;
  if (wave == 0 && hi == 0) Lpart[tile * 32 + q31] = ltot;
#pragma unroll
  for (int r2 = 0; r2 < 16; ++r2) {
    float osum = 0.f;
#pragma unroll
    for (int w = 0; w < 3; ++w) osum += ((const float*)SM[w])[lane * 17 + r2];
    const int c = (r2 & 3) + 8 * (r2 >> 2) + 4 * hi;
    Op[c * 32 + q31] = osum;
  }
  __syncthreads();
#pragma unroll
  for (int r2 = 0; r2 < 16; ++r2) Ow[lane * 17 + r2] = acc1[r2];
  __syncthreads();
#pragma unroll
  for (int r2 = 0; r2 < 16; ++r2) {
    float osum = 0.f;
#pragma unroll
    for (int w = 0; w < 3; ++w) osum += ((const float*)SM[w])[lane * 17 + r2];
    const int c = 32 + (r2 & 3) + 8 * (r2 >> 2) + 4 * hi;
    Op[c * 32 + q31] = osum;
  }
}

// ---------------------------------------------------------------- k_merge
// 576 blocks (b, jt): out = gm*(O0+O1)/(l0+l1) + x.
__global__ __launch_bounds__(256) void k_merge(const float* __restrict__ Opart,
                                               const float* __restrict__ Lpart,
                                               const float* __restrict__ x,
                                               const float* __restrict__ gamma,
                                               float* __restrict__ out) {
  __shared__ float Ls[32];
  const int t2 = blockIdx.x;              // 0..575
  const int b = t2 / 288, jt = t2 % 288;
  const int jb = jt * 32;
  const int tile0 = b * 576 + jt * 2;
  const float gm = gamma[0];
  const int t = threadIdx.x;
  if (t < 32) Ls[t] = Lpart[tile0 * 32 + t] + Lpart[(tile0 + 1) * 32 + t];
  __syncthreads();
  const float* O0 = Opart + (size_t)tile0 * 2048;
  const float* O1 = O0 + 2048;
  const float* xb = x + (size_t)b * N_C * N_PIX;
  float* ob = out + (size_t)b * N_C * N_PIX;
#pragma unroll
  for (int k = 0; k < 8; ++k) {
    const int idx = t + 256 * k;
    const int c = idx >> 5, q = idx & 31;
    const size_t gi = (size_t)c * N_PIX + jb + q;
    ob[gi] = gm * (O0[idx] + O1[idx]) / Ls[q] + xb[gi];
  }
}

// ---------------------------------------------------------------- launch
extern "C" void kernel_launch(void* const* d_in, const int* in_sizes, int n_in,
                              void* d_out, int out_size, void* d_ws, size_t ws_size,
                              hipStream_t stream) {
  const float* x     = (const float*)d_in[0];
  const float* Wq    = (const float*)d_in[1];
  const float* bq    = (const float*)d_in[2];
  const float* Wk    = (const float*)d_in[3];
  const float* bk    = (const float*)d_in[4];
  const float* Wv    = (const float*)d_in[5];
  const float* bv    = (const float*)d_in[6];
  const float* gamma = (const float*)d_in[7];
  float* out = (float*)d_out;

  char* ws = (char*)d_ws;
  float*    sig   = (float*)ws;                       // 4 floats
  unsigned* maxKu = (unsigned*)(ws + 16);             // 2 uints
  _Float16* K16   = (_Float16*)(ws + 10752);          // 294912 B
  _Float16* Q16   = (_Float16*)(ws + 10752 + 294912); // 294912 B
  _Float16* VT16  = (_Float16*)(ws + 10752 + 2 * 294912); // 2359296 B
  float*    Opart = (float*)(ws + 2960384);           // 1152*2048*4 = 9437184 B
  float*    Lpart = (float*)(ws + 2960384 + 9437184); // 1152*32*4 = 147456 B

  hipLaunchKernelGGL(k_sigma, dim3(3), dim3(64), 0, stream, Wq, Wk, Wv, sig, maxKu);
  hipLaunchKernelGGL(k_fgh, dim3(288), dim3(256), 0, stream,
                     x, Wq, bq, Wk, bk, Wv, bv, sig, K16, Q16, VT16, maxKu);
  hipLaunchKernelGGL(k_attn, dim3(1152), dim3(192), 0, stream, K16, Q16, VT16, maxKu, Opart, Lpart);
  hipLaunchKernelGGL(k_merge, dim3(576), dim3(256), 0, stream, Opart, Lpart, x, gamma, out);
}